// Round 3
// baseline (242.303 us; speedup 1.0000x reference)
//
#include <hip/hip_runtime.h>
#include <math.h>

// Problem constants (from reference): P=8 patch, N=16 slots, WS=32 window,
// B=8, C=12, H=W=512. ref_x/ref_y are runtime device scalars.
#define PP    8
#define NSEL  16
#define WSZ   32

// One block per (b,c). 256 threads.
__global__ __launch_bounds__(256) void patches_select_kernel(
    const float* __restrict__ d_re,
    const float* __restrict__ d_im,
    const int*   __restrict__ p_rx,
    const int*   __restrict__ p_ry,
    float*       __restrict__ out,
    int H, int W)
{
    const int bc   = blockIdx.x;      // b*C + c
    const int tid  = threadIdx.x;
    const int lane = tid & 63;

    const int rx = p_rx[0];
    const int ry = p_ry[0];
    const int wx0 = max(rx - WSZ / 2, 0);
    const int wx1 = min(rx + WSZ / 2, H);
    const int wy0 = max(ry - WSZ / 2, 0);
    const int wy1 = min(ry + WSZ / 2, W);
    const int Wh = wx1 - wx0;
    const int Ww = wy1 - wy0;
    const int Ph = Wh - PP + 1;
    const int Pw = Ww - PP + 1;
    const int M  = Ph * Pw;                 // <= 625
    const int Mpad = (M + 15) & ~15;        // <= 640

    __shared__ __align__(16) float sre[WSZ][WSZ];     // window, real
    __shared__ __align__(16) float sim_[WSZ][WSZ];    // window, imag
    __shared__ __align__(16) float sref[PP * PP * 2]; // ref patch, flat e-order
    __shared__ float dists[WSZ * WSZ];                // M distances + INF pad

    const size_t plane = (size_t)H * W;
    const float* baseR = d_re + (size_t)bc * plane;
    const float* baseI = d_im + (size_t)bc * plane;

    // ---- stage window into LDS ----
    if (Wh == WSZ && Ww == WSZ && ((wy0 & 3) == 0) && ((W & 3) == 0)) {
        // fast path: rows are 16B-aligned -> float4 loads (2 per thread per plane)
        const int nv = WSZ * (WSZ / 4);   // 256 float4 per plane
        for (int t = tid; t < nv; t += 256) {
            const int i = t >> 3, j4 = (t & 7) << 2;
            const size_t g = (size_t)(wx0 + i) * W + (wy0 + j4);
            *(float4*)&sre[i][j4]  = *(const float4*)&baseR[g];
            *(float4*)&sim_[i][j4] = *(const float4*)&baseI[g];
        }
    } else {
        for (int t = tid; t < Wh * Ww; t += 256) {
            const int i = t / Ww, j = t - i * Ww;
            const size_t g = (size_t)(wx0 + i) * W + (wy0 + j);
            sre[i][j]  = baseR[g];
            sim_[i][j] = baseI[g];
        }
    }
    // ---- stage reference patch, flat layout: index e = (i*PP+j)*2 + comp ----
    for (int t = tid; t < PP * PP; t += 256) {
        const int i = t / PP, j = t - i * PP;
        const size_t g = (size_t)(rx + i) * W + (ry + j);
        sref[t * 2 + 0] = baseR[g];
        sref[t * 2 + 1] = baseI[g];
    }
    // ---- pad dists[M..Mpad) with +INF (never selected: nd > INF is false) ----
    if (tid < 16 && M + tid < Mpad) dists[M + tid] = INFINITY;
    __syncthreads();

    // ---- distances: replicate numpy pairwise_sum(128) bit-exactly ----
    // numpy: 8 stride-8 accumulators r[j] over groups k=0..15 (e = 8k+j),
    // combined ((r0+r1)+(r2+r3))+((r4+r5)+(r6+r7)). k-outer/m-inner here:
    // same per-accumulator addition order, so bit-identical. Ref elements for
    // group k are sref[8k..8k+7] (contiguous) -> two ds_read_b128, hoisted
    // across this thread's patches. __f*_rn forbids FMA contraction.
    {
        int nm = 0;
        int mlist[3], mpi[3], mpj[3];
        for (int m = tid; m < M; m += 256) {
            mlist[nm] = m; mpi[nm] = m / Pw; mpj[nm] = m - (m / Pw) * Pw; ++nm;
        }
        float acc[3][8];
#pragma unroll
        for (int mm = 0; mm < 3; ++mm)
#pragma unroll
            for (int j = 0; j < 8; ++j) acc[mm][j] = 0.0f;

        const float4* ref4 = (const float4*)sref;
#pragma unroll
        for (int k = 0; k < 16; ++k) {
            const float4 ra = ref4[2 * k];
            const float4 rb = ref4[2 * k + 1];
            const int dx  = k >> 1;
            const int dyb = (k & 1) * 4;
            for (int mm = 0; mm < nm; ++mm) {
                const float* wr = &sre[mpi[mm] + dx][mpj[mm] + dyb];
                const float* wi = &sim_[mpi[mm] + dx][mpj[mm] + dyb];
                const float w0 = wr[0], w1 = wr[1], w2 = wr[2], w3 = wr[3];
                const float v0 = wi[0], v1 = wi[1], v2 = wi[2], v3 = wi[3];
                // j: 0..7 -> (comp=j&1, dyoff=j>>1); ref = sref[8k+j]
                float d;
                d = __fsub_rn(w0, ra.x); acc[mm][0] = __fadd_rn(acc[mm][0], __fmul_rn(d, d));
                d = __fsub_rn(v0, ra.y); acc[mm][1] = __fadd_rn(acc[mm][1], __fmul_rn(d, d));
                d = __fsub_rn(w1, ra.z); acc[mm][2] = __fadd_rn(acc[mm][2], __fmul_rn(d, d));
                d = __fsub_rn(v1, ra.w); acc[mm][3] = __fadd_rn(acc[mm][3], __fmul_rn(d, d));
                d = __fsub_rn(w2, rb.x); acc[mm][4] = __fadd_rn(acc[mm][4], __fmul_rn(d, d));
                d = __fsub_rn(v2, rb.y); acc[mm][5] = __fadd_rn(acc[mm][5], __fmul_rn(d, d));
                d = __fsub_rn(w3, rb.z); acc[mm][6] = __fadd_rn(acc[mm][6], __fmul_rn(d, d));
                d = __fsub_rn(v3, rb.w); acc[mm][7] = __fadd_rn(acc[mm][7], __fmul_rn(d, d));
            }
        }
        for (int mm = 0; mm < nm; ++mm) {
            const float s0 = __fadd_rn(__fadd_rn(acc[mm][0], acc[mm][1]),
                                       __fadd_rn(acc[mm][2], acc[mm][3]));
            const float s1 = __fadd_rn(__fadd_rn(acc[mm][4], acc[mm][5]),
                                       __fadd_rn(acc[mm][6], acc[mm][7]));
            const float S  = __fadd_rn(s0, s1);
            // 0.5 * (S / 128): exact power-of-two scaling.
            dists[mlist[mm]] = S * (1.0f / 256.0f);
        }
    }
    __syncthreads();

    // ---- sequential slot insertion, run redundantly by ALL 4 waves (they'd
    // otherwise idle at a barrier; results identical). Lane l<16 holds slot l.
    // For each patch m in order, the FIRST slot with nd > d gets replaced.
    // Distances prefetched in register batches of 16 (double-buffered).
    float nd = (lane < NSEL) ? 1e33f : -1.0f;  // lanes >=16 never match (d >= 0)
    int   mi = -1;
    {
        float cur[16];
#pragma unroll
        for (int u = 0; u < 16; ++u) cur[u] = dists[u];
        for (int m0 = 0; m0 < Mpad; m0 += 16) {
            float nxt[16];
            const int nb = m0 + 16;
            if (nb < Mpad) {
#pragma unroll
                for (int u = 0; u < 16; ++u) nxt[u] = dists[nb + u];
            } else {
#pragma unroll
                for (int u = 0; u < 16; ++u) nxt[u] = INFINITY;
            }
#pragma unroll
            for (int u = 0; u < 16; ++u) {
                const unsigned long long mask = __ballot(nd > cur[u]);
                const int first = __ffsll(mask) - 1;  // -1 if mask==0: no lane
                if (lane == first) { nd = cur[u]; mi = m0 + u; }
            }
#pragma unroll
            for (int u = 0; u < 16; ++u) cur[u] = nxt[u];
        }
    }
    // No barrier needed: every wave has the full result in lanes 0..15, and
    // sre/sim_ are read-only from here on.

    // ---- write 16 selected patches: thread t writes 8 contiguous floats.
    // Block output = 2048 floats; slot = tid>>4 (uniform per 16-lane group).
    const int slot = tid >> 4;
    const int m = __shfl(mi, slot);   // within-wave; all waves hold identical mi
    float* obase = out + (size_t)bc * (NSEL * PP * PP * 2) + tid * 8;
    const int rem0 = (tid & 15) * 8;  // e-offset within the 128-float patch
    float vals[8];
    if (m >= 0) {
        const int pi = m / Pw, pj = m - (m / Pw) * Pw;
#pragma unroll
        for (int q = 0; q < 8; ++q) {
            const int e = rem0 + q;
            const int kk = e >> 1, comp = e & 1;
            const int dx = kk >> 3, dy = kk & 7;
            vals[q] = comp ? sim_[pi + dx][pj + dy] : sre[pi + dx][pj + dy];
        }
    } else {
#pragma unroll
        for (int q = 0; q < 8; ++q) vals[q] = 0.0f;  // unfilled slot -> zeros
    }
    *(float4*)&obase[0] = make_float4(vals[0], vals[1], vals[2], vals[3]);
    *(float4*)&obase[4] = make_float4(vals[4], vals[5], vals[6], vals[7]);
}

extern "C" void kernel_launch(void* const* d_in, const int* in_sizes, int n_in,
                              void* d_out, int out_size, void* d_ws, size_t ws_size,
                              hipStream_t stream) {
    const float* d_re = (const float*)d_in[0];
    const float* d_im = (const float*)d_in[1];
    const int*   p_rx = (const int*)d_in[2];
    const int*   p_ry = (const int*)d_in[3];
    float* out = (float*)d_out;

    const int H = 512, W = 512;
    const int BC = in_sizes[0] / (H * W);   // 8*12 = 96

    patches_select_kernel<<<BC, 256, 0, stream>>>(d_re, d_im, p_rx, p_ry, out, H, W);
}

// Round 4
// 196.712 us; speedup vs baseline: 1.2318x; 1.2318x over previous
//
#include <hip/hip_runtime.h>
#include <math.h>

// Problem constants (from reference): P=8 patch, N=16 slots, WS=32 window,
// B=8, C=12, H=W=512. ref_x/ref_y are runtime device scalars.
#define PP    8
#define NSEL  16
#define WSZ   32

// Accumulate one k-group (8 elements) for one patch. All indices static.
// j: 0..7 -> (comp=j&1, dyoff=j>>1); ref = sref[8k+j] packed in ra/rb.
#define ACC8(A, WR, WI, OFF) do {                                         \
    const float _w0 = (WR)[(OFF)+0], _w1 = (WR)[(OFF)+1];                 \
    const float _w2 = (WR)[(OFF)+2], _w3 = (WR)[(OFF)+3];                 \
    const float _v0 = (WI)[(OFF)+0], _v1 = (WI)[(OFF)+1];                 \
    const float _v2 = (WI)[(OFF)+2], _v3 = (WI)[(OFF)+3];                 \
    float _d;                                                             \
    _d = __fsub_rn(_w0, ra.x); A[0] = __fadd_rn(A[0], __fmul_rn(_d,_d));  \
    _d = __fsub_rn(_v0, ra.y); A[1] = __fadd_rn(A[1], __fmul_rn(_d,_d));  \
    _d = __fsub_rn(_w1, ra.z); A[2] = __fadd_rn(A[2], __fmul_rn(_d,_d));  \
    _d = __fsub_rn(_v1, ra.w); A[3] = __fadd_rn(A[3], __fmul_rn(_d,_d));  \
    _d = __fsub_rn(_w2, rb.x); A[4] = __fadd_rn(A[4], __fmul_rn(_d,_d));  \
    _d = __fsub_rn(_v2, rb.y); A[5] = __fadd_rn(A[5], __fmul_rn(_d,_d));  \
    _d = __fsub_rn(_w3, rb.z); A[6] = __fadd_rn(A[6], __fmul_rn(_d,_d));  \
    _d = __fsub_rn(_v3, rb.w); A[7] = __fadd_rn(A[7], __fmul_rn(_d,_d));  \
} while (0)

// One block per (b,c). 256 threads.
__global__ __launch_bounds__(256) void patches_select_kernel(
    const float* __restrict__ d_re,
    const float* __restrict__ d_im,
    const int*   __restrict__ p_rx,
    const int*   __restrict__ p_ry,
    float*       __restrict__ out,
    int H, int W)
{
    const int bc  = blockIdx.x;      // b*C + c
    const int tid = threadIdx.x;

    const int rx = p_rx[0];
    const int ry = p_ry[0];
    const int wx0 = max(rx - WSZ / 2, 0);
    const int wx1 = min(rx + WSZ / 2, H);
    const int wy0 = max(ry - WSZ / 2, 0);
    const int wy1 = min(ry + WSZ / 2, W);
    const int Wh = wx1 - wx0;
    const int Ww = wy1 - wy0;
    const int Ph = Wh - PP + 1;
    const int Pw = Ww - PP + 1;
    const int M  = Ph * Pw;                 // <= 625
    const int Mpad = (M + 15) & ~15;        // <= 640, multiple of 16

    __shared__ __align__(16) float sre[WSZ][WSZ];     // window, real
    __shared__ __align__(16) float sim_[WSZ][WSZ];    // window, imag
    __shared__ __align__(16) float sref[PP * PP * 2]; // ref patch, flat e-order
    __shared__ __align__(16) float dists[WSZ * WSZ];  // M distances + INF pad
    __shared__ int selIdx[NSEL];

    const size_t plane = (size_t)H * W;
    const float* baseR = d_re + (size_t)bc * plane;
    const float* baseI = d_im + (size_t)bc * plane;

    // ---- stage window into LDS ----
    if (Wh == WSZ && Ww == WSZ && ((wy0 & 3) == 0) && ((W & 3) == 0)) {
        // fast path: rows 16B-aligned -> float4 loads
        const int nv = WSZ * (WSZ / 4);   // 256 float4 per plane
        for (int t = tid; t < nv; t += 256) {
            const int i = t >> 3, j4 = (t & 7) << 2;
            const size_t g = (size_t)(wx0 + i) * W + (wy0 + j4);
            *(float4*)&sre[i][j4]  = *(const float4*)&baseR[g];
            *(float4*)&sim_[i][j4] = *(const float4*)&baseI[g];
        }
    } else {
        for (int t = tid; t < Wh * Ww; t += 256) {
            const int i = t / Ww, j = t - i * Ww;
            const size_t g = (size_t)(wx0 + i) * W + (wy0 + j);
            sre[i][j]  = baseR[g];
            sim_[i][j] = baseI[g];
        }
    }
    // ---- stage reference patch, flat layout: index e = (i*PP+j)*2 + comp ----
    for (int t = tid; t < PP * PP; t += 256) {
        const int i = t / PP, j = t - i * PP;
        const size_t g = (size_t)(rx + i) * W + (ry + j);
        sref[t * 2 + 0] = baseR[g];
        sref[t * 2 + 1] = baseI[g];
    }
    // ---- pad dists[M..Mpad) with +INF (never selected: nd > INF is false) ----
    if (tid < Mpad - M) dists[M + tid] = INFINITY;
    __syncthreads();

    // ---- distances: replicate numpy pairwise_sum(128) bit-exactly ----
    // numpy: 8 stride-8 accumulators r[j] over groups k=0..15 (e = 8k+j),
    // combined ((r0+r1)+(r2+r3))+((r4+r5)+(r6+r7)). k-outer here; each thread
    // owns exactly 3 patch slots as SEPARATE named arrays (static indexing ->
    // VGPRs, no scratch; round-3's runtime-bound mm loop spilled to scratch).
    // Per-accumulator addition order (k ascending) identical -> bit-exact.
    // __f*_rn forbids FMA contraction (numpy rounds mul and add separately).
    {
        const int m0 = tid, m1 = tid + 256, m2 = tid + 512;
        const int mc0 = min(m0, M - 1), mc1 = min(m1, M - 1), mc2 = min(m2, M - 1);
        const int pi0 = mc0 / Pw, pj0 = mc0 - pi0 * Pw;
        const int pi1 = mc1 / Pw, pj1 = mc1 - pi1 * Pw;
        const int pi2 = mc2 / Pw, pj2 = mc2 - pi2 * Pw;
        const float* w0r = &sre[pi0][pj0];  const float* w0i = &sim_[pi0][pj0];
        const float* w1r = &sre[pi1][pj1];  const float* w1i = &sim_[pi1][pj1];
        const float* w2r = &sre[pi2][pj2];  const float* w2i = &sim_[pi2][pj2];

        float a0[8], a1[8], a2[8];
#pragma unroll
        for (int j = 0; j < 8; ++j) { a0[j] = 0.0f; a1[j] = 0.0f; a2[j] = 0.0f; }

        const float4* ref4 = (const float4*)sref;
#pragma unroll
        for (int k = 0; k < 16; ++k) {
            const float4 ra = ref4[2 * k];      // sref[8k..8k+3]
            const float4 rb = ref4[2 * k + 1];  // sref[8k+4..8k+7]
            const int off = (k >> 1) * WSZ + (k & 1) * 4;  // compile-time
            ACC8(a0, w0r, w0i, off);
            ACC8(a1, w1r, w1i, off);
            ACC8(a2, w2r, w2i, off);
        }
        // combine tree + 0.5*mean = S * 2^-8 (exact) ; store with guards
        {
            const float s0 = __fadd_rn(__fadd_rn(a0[0], a0[1]), __fadd_rn(a0[2], a0[3]));
            const float s1 = __fadd_rn(__fadd_rn(a0[4], a0[5]), __fadd_rn(a0[6], a0[7]));
            if (m0 < M) dists[m0] = __fadd_rn(s0, s1) * (1.0f / 256.0f);
        }
        {
            const float s0 = __fadd_rn(__fadd_rn(a1[0], a1[1]), __fadd_rn(a1[2], a1[3]));
            const float s1 = __fadd_rn(__fadd_rn(a1[4], a1[5]), __fadd_rn(a1[6], a1[7]));
            if (m1 < M) dists[m1] = __fadd_rn(s0, s1) * (1.0f / 256.0f);
        }
        {
            const float s0 = __fadd_rn(__fadd_rn(a2[0], a2[1]), __fadd_rn(a2[2], a2[3]));
            const float s1 = __fadd_rn(__fadd_rn(a2[4], a2[5]), __fadd_rn(a2[6], a2[7]));
            if (m2 < M) dists[m2] = __fadd_rn(s0, s1) * (1.0f / 256.0f);
        }
    }
    __syncthreads();

    // ---- sequential slot insertion (order-dependent), wave 0 only ----
    // Lane l<16 holds slot l; slots stay sorted non-decreasing (patience
    // invariant), so t15 = max top and an element places iff d < t15. t15 only
    // decreases -> a 16-batch with min(batch) >= t15 places nothing: skip it
    // (provably identical result). Distances prefetched as float4 batches.
    if (tid < 64) {
        float nd = (tid < NSEL) ? 1e33f : -1.0f;  // lanes >=16 never match (d>=0)
        int   mi = -1;
        float tmax = 1e33f;                       // == shfl(nd,15)
        const float4* d4 = (const float4*)dists;
        float4 c0 = d4[0], c1 = d4[1], c2 = d4[2], c3 = d4[3];
        const int NB = Mpad >> 4;
        for (int b = 0; b < NB; ++b) {
            float4 n0, n1, n2, n3;
            if (b + 1 < NB) {
                n0 = d4[4 * b + 4]; n1 = d4[4 * b + 5];
                n2 = d4[4 * b + 6]; n3 = d4[4 * b + 7];
            } else {
                n0 = n1 = n2 = n3 = make_float4(INFINITY, INFINITY, INFINITY, INFINITY);
            }
            const float bmin =
                fminf(fminf(fminf(fminf(c0.x, c0.y), fminf(c0.z, c0.w)),
                            fminf(fminf(c1.x, c1.y), fminf(c1.z, c1.w))),
                      fminf(fminf(fminf(c2.x, c2.y), fminf(c2.z, c2.w)),
                            fminf(fminf(c3.x, c3.y), fminf(c3.z, c3.w))));
            if (bmin < tmax) {   // uniform branch (cur/tmax wave-uniform)
                const int mb = b << 4;
                const float cur[16] = { c0.x, c0.y, c0.z, c0.w,
                                        c1.x, c1.y, c1.z, c1.w,
                                        c2.x, c2.y, c2.z, c2.w,
                                        c3.x, c3.y, c3.z, c3.w };
#pragma unroll
                for (int u = 0; u < 16; ++u) {
                    const unsigned long long mask = __ballot(nd > cur[u]);
                    const int first = __ffsll(mask) - 1;  // -1 if mask==0
                    if (tid == first) { nd = cur[u]; mi = mb + u; }
                }
                tmax = __shfl(nd, 15);
            }
            c0 = n0; c1 = n1; c2 = n2; c3 = n3;
        }
        if (tid < NSEL) selIdx[tid] = mi;
    }
    __syncthreads();

    // ---- write 16 selected patches: thread t writes 8 contiguous floats ----
    const int slot = tid >> 4;
    const int m = selIdx[slot];
    float* obase = out + (size_t)bc * (NSEL * PP * PP * 2) + tid * 8;
    const int rem0 = (tid & 15) * 8;  // e-offset within the 128-float patch
    float vals[8];
    if (m >= 0) {
        const int pi = m / Pw, pj = m - (m / Pw) * Pw;
#pragma unroll
        for (int q = 0; q < 8; ++q) {
            const int e = rem0 + q;
            const int kk = e >> 1, comp = e & 1;
            const int dx = kk >> 3, dy = kk & 7;
            vals[q] = comp ? sim_[pi + dx][pj + dy] : sre[pi + dx][pj + dy];
        }
    } else {
#pragma unroll
        for (int q = 0; q < 8; ++q) vals[q] = 0.0f;  // unfilled slot -> zeros
    }
    *(float4*)&obase[0] = make_float4(vals[0], vals[1], vals[2], vals[3]);
    *(float4*)&obase[4] = make_float4(vals[4], vals[5], vals[6], vals[7]);
}

extern "C" void kernel_launch(void* const* d_in, const int* in_sizes, int n_in,
                              void* d_out, int out_size, void* d_ws, size_t ws_size,
                              hipStream_t stream) {
    const float* d_re = (const float*)d_in[0];
    const float* d_im = (const float*)d_in[1];
    const int*   p_rx = (const int*)d_in[2];
    const int*   p_ry = (const int*)d_in[3];
    float* out = (float*)d_out;

    const int H = 512, W = 512;
    const int BC = in_sizes[0] / (H * W);   // 8*12 = 96

    patches_select_kernel<<<BC, 256, 0, stream>>>(d_re, d_im, p_rx, p_ry, out, H, W);
}